// Round 8
// baseline (8219.431 us; speedup 1.0000x reference)
//
#include <hip/hip_runtime.h>
#include <hip/hip_bf16.h>

#define TT 2048
typedef unsigned int uint32;
typedef unsigned long long uint64;

// ---- d_ws layout ----
// WREGF  : float [4][176][512]                    offset 0          (1441792 B)
// exSafe : uint64[2][64][4][256] {tag,f32}        after WREGF       (1048576 B)
// exFast : uint64[2][64][4][256] {tag,f32}        after exSafe      (1048576 B)
// pv     : uint32 probe[64][4] + vote[64][4]      after exFast      (2048 B)
#define WREGF_N  (4 * 176 * 512)         // 360448 floats
#define EXA_N    (2 * 64 * 4 * 256)      // 131072 qwords per buffer
#define ZQ_N     (2 * EXA_N + 256)       // qwords zeroed by prep (safe+fast+pv)

// cat k-slice for gang member g: [x[128g..+128) | s[64g..+64) | I[32g..+32)]
__device__ __forceinline__ float getA(const float* W_ih, const float* W_hh,
                                      int g, int j, int k)
{
    if (k < 128) return W_ih[j * 640 + 128 * g + k];
    if (k < 192) return W_hh[j * 256 + 64 * g + (k - 128)];
    return W_ih[j * 640 + 512 + 32 * g + (k - 192)];
}

// Weight layouts (per member g, per thread tid in [0,512)), all f32:
//  A slots i in [0,112): j = tid>>1, h = tid&1, k = 112*h + i.
//  B slots i in [112,176): p = i-112, s2 = p>>2, c = p&3, kq = tid&3,
//    n = 128g + (tid>>2), blk = (s2 + 2*kq) & 15, k = 64*kq + 4*blk + c.
__global__ void prep_kernel(const float* __restrict__ W_ih,
                            const float* __restrict__ W_hh,
                            const float* __restrict__ W_out,
                            float* __restrict__ WREGF,
                            uint64* __restrict__ zbase)
{
    int idx = blockIdx.x * blockDim.x + threadIdx.x;
    if (idx < WREGF_N) {
        int tid = idx & 511;
        int q   = idx >> 9;      // g*176 + i
        int g   = q / 176;
        int i   = q % 176;
        float v;
        if (i < 112) {
            int j = tid >> 1, h = tid & 1;
            v = getA(W_ih, W_hh, g, j, 112 * h + i);
        } else {
            int p  = i - 112;
            int s2 = p >> 2, c = p & 3;
            int kq = tid & 3;
            int n  = 128 * g + (tid >> 2);
            int blk = (s2 + 2 * kq) & 15;
            int k   = 64 * kq + 4 * blk + c;
            v = W_out[n * 256 + k];
        }
        WREGF[idx] = v;
    } else if (idx < WREGF_N + ZQ_N) {
        zbase[idx - WREGF_N] = 0ULL;   // tags/probes/votes must start 0 each launch
    }
}

// LDS-only barrier: does NOT drain vmcnt (global ops stay in flight).
__device__ __forceinline__ void bar_lds()
{
    asm volatile("s_waitcnt lgkmcnt(0)" ::: "memory");
    __builtin_amdgcn_s_barrier();
    asm volatile("" ::: "memory");
}

__device__ __forceinline__ void st64_sc0(uint64* p, uint64 v)
{
    asm volatile("global_store_dwordx2 %0, %1, off sc0" :: "v"(p), "v"(v) : "memory");
}
__device__ __forceinline__ void ld3_64_sc0(const uint64* p1, const uint64* p2,
                                           const uint64* p3,
                                           uint64& r1, uint64& r2, uint64& r3)
{
    asm volatile("global_load_dwordx2 %0, %3, off sc0\n\t"
                 "global_load_dwordx2 %1, %4, off sc0\n\t"
                 "global_load_dwordx2 %2, %5, off sc0\n\t"
                 "s_waitcnt vmcnt(0)"
                 : "=&v"(r1), "=&v"(r2), "=&v"(r3)
                 : "v"(p1), "v"(p2), "v"(p3)
                 : "memory");
}
__device__ __forceinline__ void st32_sc0(uint32* p, uint32 v)
{
    asm volatile("global_store_dword %0, %1, off sc0" :: "v"(p), "v"(v) : "memory");
}
__device__ __forceinline__ void ld3_32_sc0(const uint32* p1, const uint32* p2,
                                           const uint32* p3,
                                           uint32& r1, uint32& r2, uint32& r3)
{
    asm volatile("global_load_dword %0, %3, off sc0\n\t"
                 "global_load_dword %1, %4, off sc0\n\t"
                 "global_load_dword %2, %5, off sc0\n\t"
                 "s_waitcnt vmcnt(0)"
                 : "=&v"(r1), "=&v"(r2), "=&v"(r3)
                 : "v"(p1), "v"(p2), "v"(p3)
                 : "memory");
}

__global__ __launch_bounds__(512, 2)
void scan_kernel(const float* __restrict__ I,
                 const float* __restrict__ b_ih, const float* __restrict__ b_hh,
                 const float* __restrict__ b_out, const float* __restrict__ A,
                 const float* __restrict__ WREGF,
                 uint64* exS, uint64* exF, uint32* pv,
                 float* __restrict__ out)
{
    // act state, parity double-buffered: [x 0:128 | s 128:192 | I 192:224] floats
    __shared__ float4 aloc4[2][56];
    __shared__ float  sful[256];    // full s (redundant per WG)
    __shared__ int    l2flag;

    const int tid = threadIdx.x;
    const int bid = blockIdx.x;
    const int b   = bid & 63;     // batch element
    const int g   = bid >> 6;     // gang member
    const int g1  = (g + 1) & 3, g2 = (g + 2) & 3, g3 = (g + 3) & 3;

    // ---- weights -> VGPR as f32 (static-indexed, fully unrolled) ----
    float wAf[112], wBf[64];
    const float* wsrc = WREGF + (g * 176) * 512 + tid;
    #pragma unroll
    for (int i = 0; i < 112; ++i) wAf[i] = wsrc[i * 512];
    #pragma unroll
    for (int i = 0; i < 64; ++i)  wBf[i] = wsrc[(112 + i) * 512];

    const int h  = tid & 1;       // A k-half within lane pair
    const int jA = tid >> 1;      // A output row (per lane pair)
    const int kq = tid & 3;       // B k-quarter within lane quad
    const int nB = tid >> 2;      // B output row (per lane quad)

    const float bs   = b_ih[jA] + b_hh[jA];
    const float bo_r = ((tid & 3) == 0) ? b_out[128 * g + nB] : 0.f;
    const float Av_r = ((tid & 3) == 0) ? A[128 * g + nB] : 0.f;

    const size_t iBase   = (size_t)b * TT * 128 + 32 * g;
    const size_t outBase = (size_t)b * TT * 512 + 128 * g;

    {   // init state buffer 0: x=0, s=0, I(0)
        float* a0p = (float*)&aloc4[0][0];
        if (tid < 192) a0p[tid] = 0.f;
        else if (tid < 224) a0p[tid] = I[iBase + (tid - 192)];
    }

    // ---- startup: EMPIRICALLY validate the sc0 (same-L2) fast path ----
    // probe: bounded sc0 poll. vote: agent scope (always-live channel;
    // unbounded poll safe: every member stores its vote unconditionally).
    if (tid == 0) {
        uint32* pb = pv + b * 4;          // probe words
        uint32* vt = pv + 256 + b * 4;    // vote words
        const uint32 TOK = 0x5EED0001u;
        st32_sc0(pb + g, TOK);
        uint32 seen = 0;
        for (int it = 0; it < 4096 && seen != 7u; ++it) {
            uint32 r1, r2, r3;
            ld3_32_sc0(pb + g1, pb + g2, pb + g3, r1, r2, r3);
            if (r1 == TOK) seen |= 1u;
            if (r2 == TOK) seen |= 2u;
            if (r3 == TOK) seen |= 4u;
        }
        __hip_atomic_store(vt + g, (seen == 7u) ? 2u : 1u,
                           __ATOMIC_RELAXED, __HIP_MEMORY_SCOPE_AGENT);
        uint32 v0, v1, v2, v3;
        do {
            v0 = __hip_atomic_load(vt + 0, __ATOMIC_RELAXED, __HIP_MEMORY_SCOPE_AGENT);
            v1 = __hip_atomic_load(vt + 1, __ATOMIC_RELAXED, __HIP_MEMORY_SCOPE_AGENT);
            v2 = __hip_atomic_load(vt + 2, __ATOMIC_RELAXED, __HIP_MEMORY_SCOPE_AGENT);
            v3 = __hip_atomic_load(vt + 3, __ATOMIC_RELAXED, __HIP_MEMORY_SCOPE_AGENT);
        } while (v0 == 0u || v1 == 0u || v2 == 0u || v3 == 0u);
        l2flag = (v0 == 2u && v1 == 2u && v2 == 2u && v3 == 2u);
    }
    __syncthreads();
    const bool l2m = (l2flag != 0);
    bool fastok = l2m;                    // sticky per-thread fallback switch

    const float4* s4 = (const float4*)sful;

    for (int t = 0; t < TT; ++t) {
        const int par = t & 1;
        const float4* rd = aloc4[par];
        float*        wr = (float*)aloc4[par ^ 1];

        // issue I(t+1) prefetch early; latency hides under the whole step
        float iv = 0.f;
        if (tid < 32) {
            int tl = (t + 1 < TT) ? (t + 1) : t;
            iv = I[iBase + (size_t)tl * 128 + tid];
        }

        // ---- phase A: pre[jA] partial; lane pair covers the 224-k slice ----
        float a0 = 0.f, a1 = 0.f;
        #pragma unroll
        for (int i = 0; i < 28; ++i) {
            float4 av = rd[28 * h + i];             // 2 addrs/wave: free broadcast
            a0 = fmaf(av.x, wAf[4 * i + 0], a0);
            a1 = fmaf(av.y, wAf[4 * i + 1], a1);
            a0 = fmaf(av.z, wAf[4 * i + 2], a0);
            a1 = fmaf(av.w, wAf[4 * i + 3], a1);
        }
        float accA = a0 + a1;
        accA += __shfl_xor(accA, 1);                // h0 + h1 -> full slice partial

        const uint32 tgt = (uint32)(t + 1);
        const size_t sb  = (size_t)(par * 64 + b) * (4 * 256);

        if ((tid & 1) == 0) {
            uint64 u = ((uint64)tgt << 32) | (uint64)__float_as_uint(accA);
            // fast store into shared L2 (only meaningful if l2m), then the
            // ALWAYS-live agent-scope dup (liveness guarantee for any reader)
            if (l2m) st64_sc0(exF + sb + g * 256 + jA, u);
            __hip_atomic_store(exS + sb + g * 256 + jA, u,
                               __ATOMIC_RELAXED, __HIP_MEMORY_SCOPE_AGENT);

            const uint64* f1 = exF + sb + g1 * 256 + jA;
            const uint64* f2 = exF + sb + g2 * 256 + jA;
            const uint64* f3 = exF + sb + g3 * 256 + jA;
            const uint64* s1 = exS + sb + g1 * 256 + jA;
            const uint64* s2p = exS + sb + g2 * 256 + jA;
            const uint64* s3 = exS + sb + g3 * 256 + jA;

            float v0f = 0.f, v1f = 0.f, v2f = 0.f;
            uint32 got = 0;
            if (fastok) {                            // bounded fast poll (shared L2)
                for (int it = 0; it < 8192 && got != 7u; ++it) {
                    uint64 u1, u2, u3;
                    ld3_64_sc0(f1, f2, f3, u1, u2, u3);
                    if (!(got & 1u) && (uint32)(u1 >> 32) == tgt) { v0f = __uint_as_float((uint32)u1); got |= 1u; }
                    if (!(got & 2u) && (uint32)(u2 >> 32) == tgt) { v1f = __uint_as_float((uint32)u2); got |= 2u; }
                    if (!(got & 4u) && (uint32)(u3 >> 32) == tgt) { v2f = __uint_as_float((uint32)u3); got |= 4u; }
                }
                if (got != 7u) fastok = false;       // sticky: never spin fast again
            }
            while (got != 7u) {                      // agent poll: proven-live channel
                uint64 u1 = __hip_atomic_load(s1,  __ATOMIC_RELAXED, __HIP_MEMORY_SCOPE_AGENT);
                uint64 u2 = __hip_atomic_load(s2p, __ATOMIC_RELAXED, __HIP_MEMORY_SCOPE_AGENT);
                uint64 u3 = __hip_atomic_load(s3,  __ATOMIC_RELAXED, __HIP_MEMORY_SCOPE_AGENT);
                if (!(got & 1u) && (uint32)(u1 >> 32) == tgt) { v0f = __uint_as_float((uint32)u1); got |= 1u; }
                if (!(got & 2u) && (uint32)(u2 >> 32) == tgt) { v1f = __uint_as_float((uint32)u2); got |= 2u; }
                if (!(got & 4u) && (uint32)(u3 >> 32) == tgt) { v2f = __uint_as_float((uint32)u3); got |= 4u; }
            }

            // deterministic fixed-order sum
            float pre = accA + bs + v0f + v1f + v2f;
            // tanh(x) = 1 - 2/(exp(2x)+1): exact identity, branch-free
            float e  = __expf(2.f * pre);
            float sn = 1.f - 2.f / (e + 1.f);
            sful[jA] = sn;
            int d = jA - 64 * g;
            if (d >= 0 && d < 64) wr[128 + d] = sn;  // own s-quarter for next A
        }
        bar_lds();                                  // (1) s ready

        // ---- phase B: f[nB]; lane quad covers k=256 (rotated blocks) ----
        float c0 = 0.f, c1 = 0.f;
        #pragma unroll
        for (int s2i = 0; s2i < 16; ++s2i) {
            int blk = (s2i + 2 * kq) & 15;          // rotation: 4 distinct addrs/wave
            float4 sv = s4[16 * kq + blk];
            c0 = fmaf(sv.x, wBf[4 * s2i + 0], c0);
            c1 = fmaf(sv.y, wBf[4 * s2i + 1], c1);
            c0 = fmaf(sv.z, wBf[4 * s2i + 2], c0);
            c1 = fmaf(sv.w, wBf[4 * s2i + 3], c1);
        }
        float f = c0 + c1;
        f += __shfl_xor(f, 1);
        f += __shfl_xor(f, 2);                      // full k-sum at all quad lanes

        if ((tid & 3) == 0) {
            float ff = fmaxf(f + bo_r, 0.f);
            float xo = ((const float*)rd)[nB];
            float xn = (xo + 0.1f * ff * Av_r) / (1.1f + 0.1f * ff);
            wr[nB] = xn;                            // own x-quarter for next A
            out[outBase + (size_t)t * 512 + nB] = xn;
        }
        if (tid < 32) wr[192 + tid] = iv;           // stage I(t+1)
        bar_lds();                                  // (2) state ready for next A
    }
}

extern "C" void kernel_launch(void* const* d_in, const int* in_sizes, int n_in,
                              void* d_out, int out_size, void* d_ws, size_t ws_size,
                              hipStream_t stream)
{
    const float* I     = (const float*)d_in[0];
    const float* W_ih  = (const float*)d_in[1];
    const float* W_hh  = (const float*)d_in[2];
    const float* b_ih  = (const float*)d_in[3];
    const float* b_hh  = (const float*)d_in[4];
    const float* W_out = (const float*)d_in[5];
    const float* b_out = (const float*)d_in[6];
    const float* A     = (const float*)d_in[7];

    float*  WREGF = (float*)d_ws;
    uint64* zbase = (uint64*)(WREGF + WREGF_N);     // exSafe | exFast | pv
    uint64* exS   = zbase;
    uint64* exF   = zbase + EXA_N;
    uint32* pvp   = (uint32*)(zbase + 2 * EXA_N);

    const int total = WREGF_N + ZQ_N;
    prep_kernel<<<(total + 1023) / 1024, 1024, 0, stream>>>(W_ih, W_hh, W_out,
                                                            WREGF, zbase);
    scan_kernel<<<256, 512, 0, stream>>>(I, b_ih, b_hh, b_out, A,
                                         WREGF, exS, exF, pvp, (float*)d_out);
}